// Round 4
// baseline (276.956 us; speedup 1.0000x reference)
//
#include <hip/hip_runtime.h>
#include <math.h>

#define Hh 96
#define Ww 96
#define NPIX 9216
#define RAD 15
#define TAPS 31
#define TPB 256
#define JT 4
#define JTILE 1024          // TPB*JT
#define NJT 9               // NPIX / JTILE
#define NSPLIT 72
#define ICH 128             // NPIX / NSPLIT
#define EPSV 1e-20f

// ws layout (float offsets)
#define OFF_FEAT 0                       // 8*NPIX  (h0..h4, a, q, pad)
#define OFF_Q    (8*NPIX)                // NPIX
#define OFF_CBI  (9*NPIX)                // NPIX
#define OFF_ROWW (10*NPIX)               // 96
#define OFF_WTAB (10*NPIX+96)            // 31
#define OFF_PB   (10*NPIX+256)           // NSPLIT*NPIX
#define OFF_PC   (10*NPIX+256+NSPLIT*NPIX) // NSPLIT*NPIX

__global__ __launch_bounds__(TPB) void setup_kernel(const float* __restrict__ image,
                                                    float* __restrict__ ws){
  int n = blockIdx.x*TPB + threadIdx.x;
  if (n < NPIX){
    int y = n / Ww, x = n % Ww;
    const float c  = 0.7213475205f;   // 0.5/ln2
    const float sc = 1.2011224088f;   // sqrt(2c)
    float f0 = (float)y * (1.0f/160.0f);
    float f1 = (float)x * (1.0f/160.0f);
    float f2 = image[n]        * (1.0f/3.0f);
    float f3 = image[NPIX+n]   * (1.0f/3.0f);
    float f4 = image[2*NPIX+n] * (1.0f/3.0f);
    float a = c*(f0*f0+f1*f1+f2*f2+f3*f3+f4*f4);
    float* f8 = ws + OFF_FEAT + (size_t)n*8;
    f8[0]=sc*f0; f8[1]=sc*f1; f8[2]=sc*f2; f8[3]=sc*f3; f8[4]=sc*f4;
    f8[5]=a; f8[7]=0.f;   // slot 6 (q) written by prep each iteration
  }
  if (blockIdx.x == 0){
    int t = threadIdx.x;
    if (t < Hh){
      float s = 0.f;
      for (int yy=0; yy<Hh; ++yy){
        float d = (float)(yy - t);
        s += expf(-d*d*(1.0f/18.0f));
      }
      ws[OFF_ROWW + t] = s;   // full (untruncated) 1-D colsum
    }
    if (t >= 128 && t < 128 + TAPS){
      int d = (t - 128) - RAD;
      ws[OFF_WTAB + (t-128)] = expf(-(float)(d*d)*(1.0f/18.0f));
    }
  }
}

__global__ __launch_bounds__(TPB) void prep_kernel(const float* __restrict__ logits,
                                                   const float* __restrict__ out,
                                                   float* __restrict__ ws, int first){
  int n = blockIdx.x*TPB + threadIdx.x;
  if (n >= NPIX) return;
  const float* cur = first ? logits : out;
  float c0 = cur[n], c1 = cur[NPIX+n];
  float z = exp2f((c1 - c0) * 1.4426950408889634f);  // e^(c1-c0)
  float q = 1.0f / (1.0f + z);                       // softmax label 0
  ws[OFF_Q + n] = q;
  ws[OFF_FEAT + (size_t)n*8 + 6] = q;
}

template<int FIRST>
__global__ __launch_bounds__(TPB) void bilateral_kernel(const float* __restrict__ feat,
                                                        float* __restrict__ pB,
                                                        float* __restrict__ pC){
  __shared__ float4 lds4[ICH*2];
  int tid = threadIdx.x;
  int bj = blockIdx.x % NJT;
  int bs = blockIdx.x / NJT;

  // stage this block's 128-i chunk: 1024 floats = 256 float4
  {
    const float4* src = (const float4*)(feat + (size_t)bs*ICH*8);
    lds4[tid] = src[tid];
  }
  __syncthreads();

  float h0[JT],h1[JT],h2[JT],h3[JT],h4[JT],na[JT],accB[JT],accC[JT];
  #pragma unroll
  for (int k=0;k<JT;k++){
    int j = bj*JTILE + k*TPB + tid;
    const float4* fj = (const float4*)(feat + (size_t)j*8);
    float4 a0 = fj[0], a1 = fj[1];
    h0[k]=a0.x; h1[k]=a0.y; h2[k]=a0.z; h3[k]=a0.w;
    h4[k]=a1.x; na[k]=-a1.y;
    accB[k]=0.f; accC[k]=0.f;
  }

  #pragma unroll 4
  for (int i=0;i<ICH;i++){
    float4 w0 = lds4[i*2];      // h0..h3 of i
    float4 w1 = lds4[i*2+1];    // h4, a, q, pad
    #pragma unroll
    for (int k=0;k<JT;k++){
      float e = na[k] - w1.y;            // -(a_j + a_i)
      e = fmaf(h0[k], w0.x, e);
      e = fmaf(h1[k], w0.y, e);
      e = fmaf(h2[k], w0.z, e);
      e = fmaf(h3[k], w0.w, e);
      e = fmaf(h4[k], w1.x, e);          // e = -c*d_ij
      float kk = exp2f(e);               // v_exp_f32
      accB[k] = fmaf(kk, w1.z, accB[k]); // += q0_i * k
      if (FIRST) accC[k] += kk;          // colsum (iteration-invariant)
    }
  }

  #pragma unroll
  for (int k=0;k<JT;k++){
    int j = bj*JTILE + k*TPB + tid;
    pB[(size_t)bs*NPIX + j] = accB[k];
    if (FIRST) pC[(size_t)bs*NPIX + j] = accC[k];
  }
}

__global__ __launch_bounds__(256) void combine_kernel(const float* __restrict__ logits,
                                                      const float* __restrict__ Wsp,
                                                      const float* __restrict__ Wbi,
                                                      const float* __restrict__ Cm,
                                                      float* __restrict__ ws,
                                                      float* __restrict__ out, int first){
  __shared__ float tq[46][48];
  __shared__ float wt[TAPS];
  int tx = threadIdx.x & 15, ty = threadIdx.x >> 4;
  int bx = blockIdx.x % 6, by = blockIdx.x / 6;
  int x0 = bx*16, y0 = by*16;

  const float* q0g = ws + OFF_Q;
  for (int idx = threadIdx.x; idx < 46*46; idx += 256){
    int ly = idx / 46, lx = idx % 46;
    int gy = y0 - RAD + ly, gx = x0 - RAD + lx;
    float v = 0.f;
    if (gy >= 0 && gy < Hh && gx >= 0 && gx < Ww) v = q0g[gy*Ww + gx];
    tq[ly][lx] = v;
  }
  if (threadIdx.x < TAPS) wt[threadIdx.x] = ws[OFF_WTAB + threadIdx.x];
  __syncthreads();

  int y = y0 + ty, x = x0 + tx;
  int j = y*Ww + x;

  // truncated spatial filter of q0
  float S = 0.f;
  for (int dy=0; dy<TAPS; ++dy){
    float inner = 0.f;
    #pragma unroll
    for (int dx=0; dx<TAPS; ++dx)
      inner = fmaf(wt[dx], tq[ty+dy][tx+dx], inner);
    S = fmaf(wt[dy], inner, S);
  }

  // reduce bilateral partials
  const float* pB = ws + OFF_PB;
  float Bv = 0.f;
  for (int s=0; s<NSPLIT; ++s) Bv += pB[(size_t)s*NPIX + j];

  float Cb;
  if (first){
    const float* pC = ws + OFF_PC;
    float cb = 0.f;
    for (int s=0; s<NSPLIT; ++s) cb += pC[(size_t)s*NPIX + j];
    ws[OFF_CBI + j] = cb;
    Cb = cb;
  } else {
    Cb = ws[OFF_CBI + j];
  }

  float nb  = 1.0f/(Cb + EPSV);
  float Csp = ws[OFF_ROWW + y] * ws[OFF_ROWW + x];
  float nsp = 1.0f/(Csp + EPSV);

  float sp0 = S*nsp,       sp1 = (Csp - S)*nsp;   // q1 = 1 - q0 identity
  float bi0 = Bv*nb,       bi1 = (Cb - Bv)*nb;

  float m0 = Wsp[0]*sp0 + Wsp[1]*sp1 + Wbi[0]*bi0 + Wbi[1]*bi1;
  float m1 = Wsp[2]*sp0 + Wsp[3]*sp1 + Wbi[2]*bi0 + Wbi[3]*bi1;
  float cm0 = Cm[0]*m0 + Cm[1]*m1;
  float cm1 = Cm[2]*m0 + Cm[3]*m1;

  out[j]        = logits[j]        - cm0;
  out[NPIX + j] = logits[NPIX + j] - cm1;
}

extern "C" void kernel_launch(void* const* d_in, const int* in_sizes, int n_in,
                              void* d_out, int out_size, void* d_ws, size_t ws_size,
                              hipStream_t stream){
  const float* image  = (const float*)d_in[0];
  const float* logits = (const float*)d_in[1];
  const float* Wsp    = (const float*)d_in[2];
  const float* Wbi    = (const float*)d_in[3];
  const float* Cm     = (const float*)d_in[4];
  float* out = (float*)d_out;
  float* ws  = (float*)d_ws;

  setup_kernel<<<NPIX/TPB, TPB, 0, stream>>>(image, ws);
  for (int t=0; t<5; ++t){
    prep_kernel<<<NPIX/TPB, TPB, 0, stream>>>(logits, out, ws, t==0 ? 1 : 0);
    if (t == 0)
      bilateral_kernel<1><<<NJT*NSPLIT, TPB, 0, stream>>>(ws + OFF_FEAT, ws + OFF_PB, ws + OFF_PC);
    else
      bilateral_kernel<0><<<NJT*NSPLIT, TPB, 0, stream>>>(ws + OFF_FEAT, ws + OFF_PB, ws + OFF_PC);
    combine_kernel<<<36, 256, 0, stream>>>(logits, Wsp, Wbi, Cm, ws, out, t==0 ? 1 : 0);
  }
}

// Round 5
// 238.544 us; speedup vs baseline: 1.1610x; 1.1610x over previous
//
#include <hip/hip_runtime.h>
#include <math.h>

#define Hh 96
#define Ww 96
#define NPIX 9216
#define RAD 15
#define TAPS 31
#define TPB 256
#define JT 4
#define JTILE 1024          // TPB*JT
#define NJT 9               // NPIX / JTILE
#define NSPLIT 144
#define ICH 64              // NPIX / NSPLIT
#define EPSV 1e-20f
#define LOG2E 1.4426950408889634f

// ws layout (float offsets) — total 1,419,520 floats = 5.68 MB (same as prev round)
#define OFF_FEAT 0                       // 8*NPIX  (h0..h4, a, q, pad)
#define OFF_Q    (8*NPIX)                // NPIX
#define OFF_CBI  (9*NPIX)                // NPIX
#define OFF_ROWW (10*NPIX)               // 96
#define OFF_WTAB (10*NPIX+96)            // 31
#define OFF_PB   (10*NPIX+256)           // NSPLIT*NPIX

__global__ __launch_bounds__(TPB) void setup_kernel(const float* __restrict__ image,
                                                    float* __restrict__ ws){
  int n = blockIdx.x*TPB + threadIdx.x;
  if (n < NPIX){
    int y = n / Ww, x = n % Ww;
    const float c  = 0.7213475205f;   // 0.5/ln2
    const float sc = 1.2011224088f;   // sqrt(2c)
    float f0 = (float)y * (1.0f/160.0f);
    float f1 = (float)x * (1.0f/160.0f);
    float f2 = image[n]        * (1.0f/3.0f);
    float f3 = image[NPIX+n]   * (1.0f/3.0f);
    float f4 = image[2*NPIX+n] * (1.0f/3.0f);
    float a = c*(f0*f0+f1*f1+f2*f2+f3*f3+f4*f4);
    float* f8 = ws + OFF_FEAT + (size_t)n*8;
    f8[0]=sc*f0; f8[1]=sc*f1; f8[2]=sc*f2; f8[3]=sc*f3; f8[4]=sc*f4;
    f8[5]=a; f8[6]=0.f; f8[7]=0.f;
  }
  if (blockIdx.x == 0){
    int t = threadIdx.x;
    if (t < Hh){
      float s = 0.f;
      for (int yy=0; yy<Hh; ++yy){
        float d = (float)(yy - t);
        s += expf(-d*d*(1.0f/18.0f));
      }
      ws[OFF_ROWW + t] = s;   // full (untruncated) 1-D colsum
    }
    if (t >= 128 && t < 128 + TAPS){
      int d = (t - 128) - RAD;
      ws[OFF_WTAB + (t-128)] = expf(-(float)(d*d)*(1.0f/18.0f));
    }
  }
}

// COLSUM=1: accumulate sum_i k_ij (q ignored).  COLSUM=0: accumulate sum_i q_i*k_ij.
template<int COLSUM>
__global__ __launch_bounds__(TPB) void bilateral_kernel(const float* __restrict__ feat,
                                                        float* __restrict__ pB){
  __shared__ float4 lds4[ICH*2];
  int tid = threadIdx.x;
  int bj = blockIdx.x % NJT;
  int bs = blockIdx.x / NJT;

  // stage this block's 64-i chunk: 512 floats = 128 float4
  if (tid < ICH*2){
    const float4* src = (const float4*)(feat + (size_t)bs*ICH*8);
    lds4[tid] = src[tid];
  }
  __syncthreads();

  float h0[JT],h1[JT],h2[JT],h3[JT],h4[JT],na[JT],acc[JT];
  #pragma unroll
  for (int k=0;k<JT;k++){
    int j = bj*JTILE + k*TPB + tid;
    const float4* fj = (const float4*)(feat + (size_t)j*8);
    float4 a0 = fj[0], a1 = fj[1];
    h0[k]=a0.x; h1[k]=a0.y; h2[k]=a0.z; h3[k]=a0.w;
    h4[k]=a1.x; na[k]=-a1.y;
    acc[k]=0.f;
  }

  #pragma unroll 2
  for (int i=0;i<ICH;i++){
    float4 w0 = lds4[i*2];      // h0..h3 of i
    float4 w1 = lds4[i*2+1];    // h4, a, q, pad
    #pragma unroll
    for (int k=0;k<JT;k++){
      float e = na[k] - w1.y;            // -(a_j + a_i)
      e = fmaf(h0[k], w0.x, e);
      e = fmaf(h1[k], w0.y, e);
      e = fmaf(h2[k], w0.z, e);
      e = fmaf(h3[k], w0.w, e);
      e = fmaf(h4[k], w1.x, e);          // e = -c*d_ij  (log2 domain)
      float kk = __builtin_amdgcn_exp2f(e);  // raw v_exp_f32
      if (COLSUM) acc[k] += kk;
      else        acc[k] = fmaf(kk, w1.z, acc[k]); // += q0_i * k
    }
  }

  #pragma unroll
  for (int k=0;k<JT;k++){
    int j = bj*JTILE + k*TPB + tid;
    pB[(size_t)bs*NPIX + j] = acc[k];
  }
}

// reduce colsum partials -> CBI, and compute initial q from logits
__global__ __launch_bounds__(TPB) void prep0_kernel(const float* __restrict__ logits,
                                                    float* __restrict__ ws){
  int n = blockIdx.x*TPB + threadIdx.x;
  if (n >= NPIX) return;
  const float* pB = ws + OFF_PB;
  float cb = 0.f;
  for (int s=0; s<NSPLIT; ++s) cb += pB[(size_t)s*NPIX + n];
  ws[OFF_CBI + n] = cb;

  float c0 = logits[n], c1 = logits[NPIX+n];
  float z = __builtin_amdgcn_exp2f((c1 - c0) * LOG2E);
  float q = 1.0f / (1.0f + z);
  ws[OFF_Q + n] = q;
  ws[OFF_FEAT + (size_t)n*8 + 6] = q;
}

__global__ __launch_bounds__(256) void combine_kernel(const float* __restrict__ logits,
                                                      const float* __restrict__ Wsp,
                                                      const float* __restrict__ Wbi,
                                                      const float* __restrict__ Cm,
                                                      float* __restrict__ ws,
                                                      float* __restrict__ out){
  __shared__ float tq[46][48];
  __shared__ float wt[TAPS];
  int tx = threadIdx.x & 15, ty = threadIdx.x >> 4;
  int bx = blockIdx.x % 6, by = blockIdx.x / 6;
  int x0 = bx*16, y0 = by*16;

  const float* q0g = ws + OFF_Q;
  for (int idx = threadIdx.x; idx < 46*46; idx += 256){
    int ly = idx / 46, lx = idx % 46;
    int gy = y0 - RAD + ly, gx = x0 - RAD + lx;
    float v = 0.f;
    if (gy >= 0 && gy < Hh && gx >= 0 && gx < Ww) v = q0g[gy*Ww + gx];
    tq[ly][lx] = v;
  }
  if (threadIdx.x < TAPS) wt[threadIdx.x] = ws[OFF_WTAB + threadIdx.x];
  __syncthreads();

  int y = y0 + ty, x = x0 + tx;
  int j = y*Ww + x;

  // truncated spatial filter of q0
  float S = 0.f;
  for (int dy=0; dy<TAPS; ++dy){
    float inner = 0.f;
    #pragma unroll
    for (int dx=0; dx<TAPS; ++dx)
      inner = fmaf(wt[dx], tq[ty+dy][tx+dx], inner);
    S = fmaf(wt[dy], inner, S);
  }

  // reduce bilateral partials
  const float* pB = ws + OFF_PB;
  float Bv = 0.f;
  for (int s=0; s<NSPLIT; ++s) Bv += pB[(size_t)s*NPIX + j];

  float Cb = ws[OFF_CBI + j];
  float nb  = 1.0f/(Cb + EPSV);
  float Csp = ws[OFF_ROWW + y] * ws[OFF_ROWW + x];
  float nsp = 1.0f/(Csp + EPSV);

  float sp0 = S*nsp,       sp1 = (Csp - S)*nsp;   // q1 = 1 - q0 identity
  float bi0 = Bv*nb,       bi1 = (Cb - Bv)*nb;

  float m0 = Wsp[0]*sp0 + Wsp[1]*sp1 + Wbi[0]*bi0 + Wbi[1]*bi1;
  float m1 = Wsp[2]*sp0 + Wsp[3]*sp1 + Wbi[2]*bi0 + Wbi[3]*bi1;
  float cm0 = Cm[0]*m0 + Cm[1]*m1;
  float cm1 = Cm[2]*m0 + Cm[3]*m1;

  float o0 = logits[j]        - cm0;
  float o1 = logits[NPIX + j] - cm1;
  out[j]        = o0;
  out[NPIX + j] = o1;

  // fused softmax for the NEXT iteration (extra write on last iter is harmless)
  float z = __builtin_amdgcn_exp2f((o1 - o0) * LOG2E);
  float q = 1.0f / (1.0f + z);
  ws[OFF_Q + j] = q;
  ws[OFF_FEAT + (size_t)j*8 + 6] = q;
}

extern "C" void kernel_launch(void* const* d_in, const int* in_sizes, int n_in,
                              void* d_out, int out_size, void* d_ws, size_t ws_size,
                              hipStream_t stream){
  const float* image  = (const float*)d_in[0];
  const float* logits = (const float*)d_in[1];
  const float* Wsp    = (const float*)d_in[2];
  const float* Wbi    = (const float*)d_in[3];
  const float* Cm     = (const float*)d_in[4];
  float* out = (float*)d_out;
  float* ws  = (float*)d_ws;

  setup_kernel<<<NPIX/TPB, TPB, 0, stream>>>(image, ws);
  // iteration-invariant bilateral colsum (partials into pB, reduced by prep0)
  bilateral_kernel<1><<<NJT*NSPLIT, TPB, 0, stream>>>(ws + OFF_FEAT, ws + OFF_PB);
  prep0_kernel<<<NPIX/TPB, TPB, 0, stream>>>(logits, ws);

  for (int t=0; t<5; ++t){
    bilateral_kernel<0><<<NJT*NSPLIT, TPB, 0, stream>>>(ws + OFF_FEAT, ws + OFF_PB);
    combine_kernel<<<36, 256, 0, stream>>>(logits, Wsp, Wbi, Cm, ws, out);
  }
}